// Round 2
// baseline (869.671 us; speedup 1.0000x reference)
//
#include <hip/hip_runtime.h>
#include <hip/hip_bf16.h>

typedef float f32x4 __attribute__((ext_vector_type(4)));

#define N_NODES 100000
#define NBUK 391          // ceil(100000/256) coarse buckets of 256 nodes
#define BSHIFT 8
#define HBLK 256          // partition blocks for hist/bucketize (must match)

// ---------------- edge dtype detect: mode=1 -> int32 layout, mode=0 -> int64 (low/high words) ----
__global__ void k_detect(const int* __restrict__ ei, int* __restrict__ mode) {
    __shared__ int flag;
    if (threadIdx.x == 0) flag = 0;
    __syncthreads();
    int f = 0;
    for (int i = threadIdx.x; i < 4096; i += 256)
        if (ei[2 * i + 1] != 0) f = 1;
    if (f) flag = 1;   // benign race: all writers store 1
    __syncthreads();
    if (threadIdx.x == 0) *mode = flag;
}

// ---------------- coarse histogram: per-block LDS hist, NO global atomics ----------------
__global__ __launch_bounds__(256) void k_hist(const int* __restrict__ ei,
                                              const int* __restrict__ mode,
                                              int* __restrict__ gh, int E, int chunk) {
    __shared__ int hist[NBUK];
    int tid = threadIdx.x, k = blockIdx.x;
    for (int b = tid; b < NBUK; b += 256) hist[b] = 0;
    __syncthreads();
    int m = *mode;
    int e0 = k * chunk, e1 = min(E, e0 + chunk);
    for (int e = e0 + tid; e < e1; e += 256) {
        int d = m ? ei[E + e] : ei[2 * (E + e)];
        if ((unsigned)d >= N_NODES) d = 0;
        atomicAdd(&hist[d >> BSHIFT], 1);   // LDS atomic
    }
    __syncthreads();
    for (int b = tid; b < NBUK; b += 256) gh[k * NBUK + b] = hist[b];
}

// ---------------- per-bucket totals (391 blocks) ----------------
__global__ __launch_bounds__(256) void k_btot(const int* __restrict__ gh, int* __restrict__ btot) {
    __shared__ int s[256];
    int b = blockIdx.x, tid = threadIdx.x;
    s[tid] = gh[tid * NBUK + b];
    __syncthreads();
    for (int d = 128; d > 0; d >>= 1) {
        if (tid < d) s[tid] += s[tid + d];
        __syncthreads();
    }
    if (tid == 0) btot[b] = s[0];
}

// ---------------- scan of bucket totals -> bucket bases ----------------
__global__ void k_scan_btot(const int* __restrict__ btot, int* __restrict__ bbase,
                            int* __restrict__ rowptr, int E) {
    __shared__ int s[512];
    int tid = threadIdx.x;
    int v = (tid < NBUK) ? btot[tid] : 0;
    s[tid] = v;
    __syncthreads();
    for (int d = 1; d < 512; d <<= 1) {
        int t = (tid >= d) ? s[tid - d] : 0;
        __syncthreads();
        s[tid] += t;
        __syncthreads();
    }
    if (tid < NBUK) bbase[tid] = s[tid] - v;   // exclusive
    if (tid == 0) { bbase[NBUK] = E; rowptr[N_NODES] = E; }
}

// ---------------- per-bucket column scans: gh -> per-(block,bucket) write offsets (in place) ----
__global__ __launch_bounds__(256) void k_scan_cols(int* __restrict__ gh, const int* __restrict__ bbase) {
    __shared__ int s[256];
    int b = blockIdx.x, tid = threadIdx.x;
    int v = gh[tid * NBUK + b];
    s[tid] = v;
    __syncthreads();
    for (int d = 1; d < 256; d <<= 1) {
        int t = (tid >= d) ? s[tid - d] : 0;
        __syncthreads();
        s[tid] += t;
        __syncthreads();
    }
    gh[tid * NBUK + b] = bbase[b] + s[tid] - v;
}

// ---------------- bucketize: ranked scatter into coarse buckets, LDS cursors only ----------------
__global__ __launch_bounds__(256) void k_bucketize(const int* __restrict__ ei,
                                                   const int* __restrict__ mode,
                                                   const int* __restrict__ offs,
                                                   int2* __restrict__ bp, int E, int chunk) {
    __shared__ int cur[NBUK];
    int tid = threadIdx.x, k = blockIdx.x;
    for (int b = tid; b < NBUK; b += 256) cur[b] = offs[k * NBUK + b];
    __syncthreads();
    int m = *mode;
    int e0 = k * chunk, e1 = min(E, e0 + chunk);
    for (int e = e0 + tid; e < e1; e += 256) {
        int s, d;
        if (m) { s = ei[e]; d = ei[E + e]; }
        else   { s = ei[2 * e]; d = ei[2 * (E + e)]; }
        if ((unsigned)s >= N_NODES) s = 0;
        if ((unsigned)d >= N_NODES) d = 0;
        int pos = atomicAdd(&cur[d >> BSHIFT], 1);   // LDS atomic
        int2 p; p.x = s; p.y = d;
        bp[pos] = p;
    }
}

// ---------------- per-bucket CSR build: LDS counts/scan/cursors, writes rowptr+dinv+csr ----------
__global__ __launch_bounds__(256) void k_build_csr(const int2* __restrict__ bp,
                                                   const int* __restrict__ bbase,
                                                   int* __restrict__ rowptr,
                                                   float* __restrict__ dinv,
                                                   int* __restrict__ csr) {
    __shared__ int cnt[256];
    __shared__ int s[256];
    __shared__ int cur[256];
    int b = blockIdx.x, tid = threadIdx.x;
    int nb = b << BSHIFT;
    int estart = bbase[b], eend = bbase[b + 1];
    cnt[tid] = 0;
    __syncthreads();
    for (int e = estart + tid; e < eend; e += 256) {
        int2 p = bp[e];
        atomicAdd(&cnt[p.y - nb], 1);   // LDS atomic
    }
    __syncthreads();
    int v = cnt[tid];
    s[tid] = v;
    __syncthreads();
    for (int d = 1; d < 256; d <<= 1) {
        int t = (tid >= d) ? s[tid - d] : 0;
        __syncthreads();
        s[tid] += t;
        __syncthreads();
    }
    int excl = s[tid] - v;
    int node = nb + tid;
    if (node < N_NODES) {
        rowptr[node] = estart + excl;
        dinv[node] = rsqrtf((float)v + 1.0f);
    }
    cur[tid] = estart + excl;
    __syncthreads();
    for (int e = estart + tid; e < eend; e += 256) {
        int2 p = bp[e];
        int pos = atomicAdd(&cur[p.y - nb], 1);   // LDS atomic
        csr[pos] = p.x;
    }
}

// ---------------- GEMM1 v2: H_pre[100000,32] = (X @ W) * dinv ----------------
// Each thread owns ONE output row: acc[32] in VGPRs, no split-K, no LDS reduce.
// W[k,0:32] is wave-uniform -> compiler scalarizes to s_load (scalar pipe),
// so the vector pipe runs nearly pure FMA (old version: 8x ds_read_b128 of W
// per kk ~= 96 LDS-cycles against 64 FMA-cycles -> LDS-issue bound, VALU 19%).
// X staged in LDS [256 rows][KC=16], row stride 20 dwords: 16B-aligned for
// b128 and bank-uniform (20*r mod 32 hits 8 disjoint 4-bank groups).
#define G1_KC 16
#define G1_ROWS 256
__global__ __launch_bounds__(256) void k_gemm1(const float* __restrict__ X,
                                               const float* __restrict__ W,
                                               const float* __restrict__ dinv,
                                               float* __restrict__ H) {
    __shared__ float xs[G1_ROWS * 20];   // 20 KB
    int tid = threadIdx.x;
    long row0 = (long)blockIdx.x * G1_ROWS;
    long myrow = row0 + tid;

    float acc[32];
#pragma unroll
    for (int c = 0; c < 32; c++) acc[c] = 0.f;

    for (int k0 = 0; k0 < 512; k0 += G1_KC) {
        __syncthreads();
        // stage X[row0:row0+256, k0:k0+16]: 4096 dwords, 4x f32x4 per thread
#pragma unroll
        for (int u = 0; u < 4; u++) {
            int idx = u * 256 + tid;
            int rr = idx >> 2, j = idx & 3;
            long grow = row0 + rr;
            f32x4 v = {0.f, 0.f, 0.f, 0.f};
            if (grow < N_NODES) v = *(const f32x4*)&X[grow * 512 + k0 + 4 * j];
            *(f32x4*)&xs[rr * 20 + 4 * j] = v;
        }
        __syncthreads();
#pragma unroll
        for (int kk = 0; kk < G1_KC; kk += 4) {
            f32x4 xq = *(const f32x4*)&xs[tid * 20 + kk];
            const float* wbase = &W[(long)(k0 + kk) * 32];
#pragma unroll
            for (int q = 0; q < 4; q++) {
                float xk = xq[q];
#pragma unroll
                for (int c = 0; c < 32; c++)
                    acc[c] = fmaf(xk, wbase[q * 32 + c], acc[c]);
            }
        }
    }
    if (myrow < N_NODES) {
        float dv = dinv[myrow];
        float* out = &H[myrow * 32];
#pragma unroll
        for (int c = 0; c < 32; c += 4) {
            f32x4 v;
            v.x = acc[c] * dv; v.y = acc[c + 1] * dv;
            v.z = acc[c + 2] * dv; v.w = acc[c + 3] * dv;
            *(f32x4*)&out[c] = v;
        }
    }
}

// ---------------- shared gather core: asum = sum_{e} H_pre[csr[e]*32+f] ----------------
__device__ __forceinline__ float gather_sum(const float* __restrict__ Hf,
                                            const int* __restrict__ csr,
                                            int e0, int e1, int f) {
    float a0 = 0.f, a1 = 0.f, a2 = 0.f, a3 = 0.f;
    for (int base = e0; base < e1; base += 32) {
        int idx = base + f;
        int sl = (idx < e1) ? csr[idx] : 0;    // one coalesced 32-wide load
        int mm = e1 - base;
        if (mm >= 32) {
#pragma unroll
            for (int j = 0; j < 32; j += 4) {
                int s0 = __shfl(sl, j, 32);
                int s1 = __shfl(sl, j + 1, 32);
                int s2 = __shfl(sl, j + 2, 32);
                int s3 = __shfl(sl, j + 3, 32);
                a0 += Hf[(long)s0 * 32];
                a1 += Hf[(long)s1 * 32];
                a2 += Hf[(long)s2 * 32];
                a3 += Hf[(long)s3 * 32];
            }
        } else {
            for (int j = 0; j < mm; j++) {
                int s0 = __shfl(sl, j, 32);
                a0 += Hf[(long)s0 * 32];
            }
        }
    }
    return (a0 + a1) + (a2 + a3);
}

// ---------------- fused: x = relu(dv*(agg+self)+b); Hout_pre = (x @ W) * dv ----------------
__global__ __launch_bounds__(256) void k_agg_mm(const float* __restrict__ H,
                                                const int* __restrict__ rowptr,
                                                const int* __restrict__ csr,
                                                const float* __restrict__ dinv,
                                                const float* __restrict__ bias,
                                                const float* __restrict__ W,
                                                float* __restrict__ Hout, int n) {
    __shared__ float ws[1024];
    int tid = threadIdx.x;
    for (int t = tid; t < 1024; t += 256) ws[t] = W[t];
    __syncthreads();
    int node = blockIdx.x * 8 + (tid >> 5);
    int f = tid & 31;
    if (node >= n) return;
    int e0 = rowptr[node], e1 = rowptr[node + 1];
    const float* Hf = H + f;
    float asum = gather_sum(Hf, csr, e0, e1, f);
    float dv = dinv[node];
    float v = dv * (asum + Hf[(long)node * 32]) + bias[f];
    v = fmaxf(v, 0.f);
    float o = 0.f;
#pragma unroll
    for (int k = 0; k < 32; k++) {
        float vk = __shfl(v, k, 32);
        o += vk * ws[k * 32 + f];
    }
    Hout[(long)node * 32 + f] = o * dv;
}

// ---------------- fused: x3 = relu(dv*(agg+self)+b); out = relu(x3@lin1+b1)@lin2+b2 ----------------
__global__ __launch_bounds__(256) void k_agg_head(const float* __restrict__ H,
                                                  const int* __restrict__ rowptr,
                                                  const int* __restrict__ csr,
                                                  const float* __restrict__ dinv,
                                                  const float* __restrict__ bias,
                                                  const float* __restrict__ L1W,
                                                  const float* __restrict__ L1B,
                                                  const float* __restrict__ L2W,
                                                  const float* __restrict__ L2B,
                                                  float* __restrict__ out, int n) {
    __shared__ float w1[512];   // [32][16]
    __shared__ float w2[160];   // [16][10]
    __shared__ float bb1[16];
    __shared__ float bb2[10];
    int tid = threadIdx.x;
    for (int t = tid; t < 512; t += 256) w1[t] = L1W[t];
    if (tid < 160) w2[tid] = L2W[tid];
    if (tid < 16) bb1[tid] = L1B[tid];
    if (tid < 10) bb2[tid] = L2B[tid];
    __syncthreads();
    int node = blockIdx.x * 8 + (tid >> 5);
    int f = tid & 31;
    if (node >= n) return;
    int e0 = rowptr[node], e1 = rowptr[node + 1];
    const float* Hf = H + f;
    float asum = gather_sum(Hf, csr, e0, e1, f);
    float dv = dinv[node];
    float v = dv * (asum + Hf[(long)node * 32]) + bias[f];
    v = fmaxf(v, 0.f);
    int c1 = f & 15;
    float t1 = 0.f;
#pragma unroll
    for (int k = 0; k < 32; k++) {
        float vk = __shfl(v, k, 32);
        t1 += vk * w1[k * 16 + c1];
    }
    t1 = fmaxf(t1 + bb1[c1], 0.f);
    int c2 = (f < 10) ? f : 0;
    float o = 0.f;
#pragma unroll
    for (int k = 0; k < 16; k++) {
        float tk = __shfl(t1, k, 32);
        o += tk * w2[k * 10 + c2];
    }
    o += bb2[c2];
    if (f < 10) out[(long)node * 10 + f] = o;
}

extern "C" void kernel_launch(void* const* d_in, const int* in_sizes, int n_in,
                              void* d_out, int out_size, void* d_ws, size_t ws_size,
                              hipStream_t stream) {
    const float* x0 = (const float*)d_in[0];
    const int* ei = (const int*)d_in[1];
    const float* W1 = (const float*)d_in[3];
    const float* b1 = (const float*)d_in[4];
    const float* W2 = (const float*)d_in[5];
    const float* b2 = (const float*)d_in[6];
    const float* W3 = (const float*)d_in[7];
    const float* b3 = (const float*)d_in[8];
    const float* l1W = (const float*)d_in[9];
    const float* l1b = (const float*)d_in[10];
    const float* l2W = (const float*)d_in[11];
    const float* l2b = (const float*)d_in[12];

    const int E = in_sizes[1] / 2;
    const int N = N_NODES;

    char* w = (char*)d_ws;
    // bp (25.6 MB) aliases h+xb: dead before k_gemm1 writes h.
    float* h      = (float*)(w);                   // 12,800,000 B
    float* xb     = (float*)(w + 12800000);        // 12,800,000 B
    int2*  bp     = (int2*) (w);                   // 25,600,000 B (alias)
    int*   gh     = (int*)  (w + 25600000);        //    400,384 B  (HBLK*NBUK)
    int*   btot   = (int*)  (w + 26000384);        //      1,564 B
    int*   bbase  = (int*)  (w + 26001948);        //      1,568 B  (NBUK+1)
    int*   rowptr = (int*)  (w + 26003516);        //    400,016 B
    float* dinv   = (float*)(w + 26403532);        //    400,000 B
    int*   csr    = (int*)  (w + 26803532);        // 12,800,000 B
    int*   mode   = (int*)  (w + 39603532);        //          4 B

    const int chunk = (E + HBLK - 1) / HBLK;   // 12500
    const int AGB = (N + 7) / 8;               // 12500
    const int G1B = (N + G1_ROWS - 1) / G1_ROWS;  // 391

    // --- CSR build: zero global atomics ---
    k_detect<<<1, 256, 0, stream>>>(ei, mode);
    k_hist<<<HBLK, 256, 0, stream>>>(ei, mode, gh, E, chunk);
    k_btot<<<NBUK, 256, 0, stream>>>(gh, btot);
    k_scan_btot<<<1, 512, 0, stream>>>(btot, bbase, rowptr, E);
    k_scan_cols<<<NBUK, 256, 0, stream>>>(gh, bbase);
    k_bucketize<<<HBLK, 256, 0, stream>>>(ei, mode, gh, bp, E, chunk);
    k_build_csr<<<NBUK, 256, 0, stream>>>(bp, bbase, rowptr, dinv, csr);

    // --- layers (transform + head fused into aggregation epilogues; H pre-scaled by dinv) ---
    k_gemm1<<<G1B, 256, 0, stream>>>(x0, W1, dinv, h);
    k_agg_mm<<<AGB, 256, 0, stream>>>(h, rowptr, csr, dinv, b1, W2, xb, N);
    k_agg_mm<<<AGB, 256, 0, stream>>>(xb, rowptr, csr, dinv, b2, W3, h, N);
    k_agg_head<<<AGB, 256, 0, stream>>>(h, rowptr, csr, dinv, b3,
                                        l1W, l1b, l2W, l2b, (float*)d_out, N);
}

// Round 3
// 762.691 us; speedup vs baseline: 1.1403x; 1.1403x over previous
//
#include <hip/hip_runtime.h>
#include <hip/hip_bf16.h>

typedef float f32x4 __attribute__((ext_vector_type(4)));
typedef short bf16x8 __attribute__((ext_vector_type(8)));

#define N_NODES 100000
#define NBUK 391          // ceil(100000/256) coarse buckets of 256 nodes
#define BSHIFT 8
#define HBLK 256          // partition blocks for hist/bucketize (must match)

// ---------------- edge dtype detect: mode=1 -> int32 layout, mode=0 -> int64 (low/high words) ----
__global__ void k_detect(const int* __restrict__ ei, int* __restrict__ mode) {
    __shared__ int flag;
    if (threadIdx.x == 0) flag = 0;
    __syncthreads();
    int f = 0;
    for (int i = threadIdx.x; i < 4096; i += 256)
        if (ei[2 * i + 1] != 0) f = 1;
    if (f) flag = 1;   // benign race: all writers store 1
    __syncthreads();
    if (threadIdx.x == 0) *mode = flag;
}

// ---------------- coarse histogram: per-block LDS hist, NO global atomics ----------------
__global__ __launch_bounds__(256) void k_hist(const int* __restrict__ ei,
                                              const int* __restrict__ mode,
                                              int* __restrict__ gh, int E, int chunk) {
    __shared__ int hist[NBUK];
    int tid = threadIdx.x, k = blockIdx.x;
    for (int b = tid; b < NBUK; b += 256) hist[b] = 0;
    __syncthreads();
    int m = *mode;
    int e0 = k * chunk, e1 = min(E, e0 + chunk);
    for (int e = e0 + tid; e < e1; e += 256) {
        int d = m ? ei[E + e] : ei[2 * (E + e)];
        if ((unsigned)d >= N_NODES) d = 0;
        atomicAdd(&hist[d >> BSHIFT], 1);   // LDS atomic
    }
    __syncthreads();
    for (int b = tid; b < NBUK; b += 256) gh[k * NBUK + b] = hist[b];
}

// ---------------- per-bucket totals (391 blocks) ----------------
__global__ __launch_bounds__(256) void k_btot(const int* __restrict__ gh, int* __restrict__ btot) {
    __shared__ int s[256];
    int b = blockIdx.x, tid = threadIdx.x;
    s[tid] = gh[tid * NBUK + b];
    __syncthreads();
    for (int d = 128; d > 0; d >>= 1) {
        if (tid < d) s[tid] += s[tid + d];
        __syncthreads();
    }
    if (tid == 0) btot[b] = s[0];
}

// ---------------- scan of bucket totals -> bucket bases ----------------
__global__ void k_scan_btot(const int* __restrict__ btot, int* __restrict__ bbase,
                            int* __restrict__ rowptr, int E) {
    __shared__ int s[512];
    int tid = threadIdx.x;
    int v = (tid < NBUK) ? btot[tid] : 0;
    s[tid] = v;
    __syncthreads();
    for (int d = 1; d < 512; d <<= 1) {
        int t = (tid >= d) ? s[tid - d] : 0;
        __syncthreads();
        s[tid] += t;
        __syncthreads();
    }
    if (tid < NBUK) bbase[tid] = s[tid] - v;   // exclusive
    if (tid == 0) { bbase[NBUK] = E; rowptr[N_NODES] = E; }
}

// ---------------- per-bucket column scans: gh -> per-(block,bucket) write offsets (in place) ----
__global__ __launch_bounds__(256) void k_scan_cols(int* __restrict__ gh, const int* __restrict__ bbase) {
    __shared__ int s[256];
    int b = blockIdx.x, tid = threadIdx.x;
    int v = gh[tid * NBUK + b];
    s[tid] = v;
    __syncthreads();
    for (int d = 1; d < 256; d <<= 1) {
        int t = (tid >= d) ? s[tid - d] : 0;
        __syncthreads();
        s[tid] += t;
        __syncthreads();
    }
    gh[tid * NBUK + b] = bbase[b] + s[tid] - v;
}

// ---------------- bucketize: ranked scatter into coarse buckets, LDS cursors only ----------------
__global__ __launch_bounds__(256) void k_bucketize(const int* __restrict__ ei,
                                                   const int* __restrict__ mode,
                                                   const int* __restrict__ offs,
                                                   int2* __restrict__ bp, int E, int chunk) {
    __shared__ int cur[NBUK];
    int tid = threadIdx.x, k = blockIdx.x;
    for (int b = tid; b < NBUK; b += 256) cur[b] = offs[k * NBUK + b];
    __syncthreads();
    int m = *mode;
    int e0 = k * chunk, e1 = min(E, e0 + chunk);
    for (int e = e0 + tid; e < e1; e += 256) {
        int s, d;
        if (m) { s = ei[e]; d = ei[E + e]; }
        else   { s = ei[2 * e]; d = ei[2 * (E + e)]; }
        if ((unsigned)s >= N_NODES) s = 0;
        if ((unsigned)d >= N_NODES) d = 0;
        int pos = atomicAdd(&cur[d >> BSHIFT], 1);   // LDS atomic
        int2 p; p.x = s; p.y = d;
        bp[pos] = p;
    }
}

// ---------------- per-bucket CSR build: LDS counts/scan/cursors, writes rowptr+dinv+csr ----------
__global__ __launch_bounds__(256) void k_build_csr(const int2* __restrict__ bp,
                                                   const int* __restrict__ bbase,
                                                   int* __restrict__ rowptr,
                                                   float* __restrict__ dinv,
                                                   int* __restrict__ csr) {
    __shared__ int cnt[256];
    __shared__ int s[256];
    __shared__ int cur[256];
    int b = blockIdx.x, tid = threadIdx.x;
    int nb = b << BSHIFT;
    int estart = bbase[b], eend = bbase[b + 1];
    cnt[tid] = 0;
    __syncthreads();
    for (int e = estart + tid; e < eend; e += 256) {
        int2 p = bp[e];
        atomicAdd(&cnt[p.y - nb], 1);   // LDS atomic
    }
    __syncthreads();
    int v = cnt[tid];
    s[tid] = v;
    __syncthreads();
    for (int d = 1; d < 256; d <<= 1) {
        int t = (tid >= d) ? s[tid - d] : 0;
        __syncthreads();
        s[tid] += t;
        __syncthreads();
    }
    int excl = s[tid] - v;
    int node = nb + tid;
    if (node < N_NODES) {
        rowptr[node] = estart + excl;
        dinv[node] = rsqrtf((float)v + 1.0f);
    }
    cur[tid] = estart + excl;
    __syncthreads();
    for (int e = estart + tid; e < eend; e += 256) {
        int2 p = bp[e];
        int pos = atomicAdd(&cur[p.y - nb], 1);   // LDS atomic
        csr[pos] = p.x;
    }
}

// ---------------- bf16 split helpers (RNE) ----------------
__device__ __forceinline__ unsigned short f2bf(float x) {
    unsigned u = __float_as_uint(x);
    unsigned lsb = (u >> 16) & 1;
    u += 0x7fffu + lsb;
    return (unsigned short)(u >> 16);
}
__device__ __forceinline__ float bf2f(unsigned short h) {
    return __uint_as_float(((unsigned)h) << 16);
}

// ---------------- prep: split W1 into bf16 hi/lo MFMA B-fragments ----------------
// Fragment order (k-map f(kg,i) = kg*8 + i, identical for A and B so any k-perm cancels):
//   out dword idx = ((kc*2 + ct)*64 + lane)*4 + dw ;  lane = kg*16 + c
//   packs bf16 of W[kc*32 + kg*8 + (2dw)][ct*16 + c] (lo) and ...(2dw+1) (hi)
__global__ __launch_bounds__(256) void k_prepw(const float* __restrict__ W,
                                               unsigned* __restrict__ Bh,
                                               unsigned* __restrict__ Bl) {
    int idx = blockIdx.x * 256 + threadIdx.x;     // 16*2*64*4 = 8192 dwords
    if (idx >= 8192) return;
    int dw = idx & 3, lane = (idx >> 2) & 63, ct = (idx >> 8) & 1, kc = idx >> 9;
    int c = lane & 15, kg = lane >> 4;
    int col = ct * 16 + c;
    unsigned h01 = 0, l01 = 0;
#pragma unroll
    for (int e = 0; e < 2; e++) {
        int k = kc * 32 + kg * 8 + dw * 2 + e;
        float w = W[k * 32 + col];
        unsigned short wh = f2bf(w);
        unsigned short wl = f2bf(w - bf2f(wh));
        h01 |= ((unsigned)wh) << (16 * e);
        l01 |= ((unsigned)wl) << (16 * e);
    }
    Bh[idx] = h01;
    Bl[idx] = l01;
}

// ---------------- GEMM1 v3 (MFMA bf16-split): H_pre = (X @ W1) * dinv ----------------
// X@W = Xh@Wh + Xl@Wh + Xh@Wl (Xl@Wl dropped: ~2^-16 rel). fp32 accumulate in MFMA.
// Per wave: 16 rows x 32 cols. No LDS, no barriers, 6250 independent waves.
// A-frag: lane l: row = l&15, elems i -> X[row][kc*32 + (l>>4)*8 + i]  (same k-map as B).
// C/D (m89-verified): col = lane&15, row = (lane>>4)*4 + j.
__global__ __launch_bounds__(256) void k_gemm1(const float* __restrict__ X,
                                               const unsigned* __restrict__ Bh,
                                               const unsigned* __restrict__ Bl,
                                               const float* __restrict__ dinv,
                                               float* __restrict__ H) {
    int tid = threadIdx.x;
    int lane = tid & 63;
    int wv = tid >> 6;
    long r0 = (long)blockIdx.x * 64 + wv * 16;
    if (r0 >= N_NODES) return;            // 100000 % 16 == 0: waves are all-or-nothing
    int row = lane & 15, kg = lane >> 4;
    const float* xrow = X + (r0 + row) * 512 + kg * 8;

    f32x4 acc0 = {0.f, 0.f, 0.f, 0.f};
    f32x4 acc1 = {0.f, 0.f, 0.f, 0.f};

    for (int kc = 0; kc < 16; kc++) {
        f32x4 xa = *(const f32x4*)(xrow + kc * 32);
        f32x4 xb = *(const f32x4*)(xrow + kc * 32 + 4);
        float xv[8] = {xa.x, xa.y, xa.z, xa.w, xb.x, xb.y, xb.z, xb.w};
        bf16x8 ah, al;
#pragma unroll
        for (int i = 0; i < 8; i++) {
            unsigned short h = f2bf(xv[i]);
            ah[i] = (short)h;
            al[i] = (short)f2bf(xv[i] - bf2f(h));
        }
        const bf16x8 bh0 = *(const bf16x8*)(Bh + ((kc * 2 + 0) * 64 + lane) * 4);
        const bf16x8 bh1 = *(const bf16x8*)(Bh + ((kc * 2 + 1) * 64 + lane) * 4);
        const bf16x8 bl0 = *(const bf16x8*)(Bl + ((kc * 2 + 0) * 64 + lane) * 4);
        const bf16x8 bl1 = *(const bf16x8*)(Bl + ((kc * 2 + 1) * 64 + lane) * 4);
        acc0 = __builtin_amdgcn_mfma_f32_16x16x32_bf16(ah, bh0, acc0, 0, 0, 0);
        acc1 = __builtin_amdgcn_mfma_f32_16x16x32_bf16(ah, bh1, acc1, 0, 0, 0);
        acc0 = __builtin_amdgcn_mfma_f32_16x16x32_bf16(al, bh0, acc0, 0, 0, 0);
        acc1 = __builtin_amdgcn_mfma_f32_16x16x32_bf16(al, bh1, acc1, 0, 0, 0);
        acc0 = __builtin_amdgcn_mfma_f32_16x16x32_bf16(ah, bl0, acc0, 0, 0, 0);
        acc1 = __builtin_amdgcn_mfma_f32_16x16x32_bf16(ah, bl1, acc1, 0, 0, 0);
    }

    int c = lane & 15;
#pragma unroll
    for (int j = 0; j < 4; j++) {
        long grow = r0 + kg * 4 + j;
        float dv = dinv[grow];
        H[grow * 32 + c]      = acc0[j] * dv;
        H[grow * 32 + 16 + c] = acc1[j] * dv;
    }
}

// ---------------- shared gather core: asum = sum_{e} H_pre[csr[e]*32+f] ----------------
__device__ __forceinline__ float gather_sum(const float* __restrict__ Hf,
                                            const int* __restrict__ csr,
                                            int e0, int e1, int f) {
    float a0 = 0.f, a1 = 0.f, a2 = 0.f, a3 = 0.f;
    for (int base = e0; base < e1; base += 32) {
        int idx = base + f;
        int sl = (idx < e1) ? csr[idx] : 0;    // one coalesced 32-wide load
        int mm = e1 - base;
        if (mm >= 32) {
#pragma unroll
            for (int j = 0; j < 32; j += 4) {
                int s0 = __shfl(sl, j, 32);
                int s1 = __shfl(sl, j + 1, 32);
                int s2 = __shfl(sl, j + 2, 32);
                int s3 = __shfl(sl, j + 3, 32);
                a0 += Hf[(long)s0 * 32];
                a1 += Hf[(long)s1 * 32];
                a2 += Hf[(long)s2 * 32];
                a3 += Hf[(long)s3 * 32];
            }
        } else {
            for (int j = 0; j < mm; j++) {
                int s0 = __shfl(sl, j, 32);
                a0 += Hf[(long)s0 * 32];
            }
        }
    }
    return (a0 + a1) + (a2 + a3);
}

// ---------------- fused: x = relu(dv*(agg+self)+b); Hout_pre = (x @ W) * dv ----------------
__global__ __launch_bounds__(256) void k_agg_mm(const float* __restrict__ H,
                                                const int* __restrict__ rowptr,
                                                const int* __restrict__ csr,
                                                const float* __restrict__ dinv,
                                                const float* __restrict__ bias,
                                                const float* __restrict__ W,
                                                float* __restrict__ Hout, int n) {
    __shared__ float ws[1024];
    int tid = threadIdx.x;
    for (int t = tid; t < 1024; t += 256) ws[t] = W[t];
    __syncthreads();
    int node = blockIdx.x * 8 + (tid >> 5);
    int f = tid & 31;
    if (node >= n) return;
    int e0 = rowptr[node], e1 = rowptr[node + 1];
    const float* Hf = H + f;
    float asum = gather_sum(Hf, csr, e0, e1, f);
    float dv = dinv[node];
    float v = dv * (asum + Hf[(long)node * 32]) + bias[f];
    v = fmaxf(v, 0.f);
    float o = 0.f;
#pragma unroll
    for (int k = 0; k < 32; k++) {
        float vk = __shfl(v, k, 32);
        o += vk * ws[k * 32 + f];
    }
    Hout[(long)node * 32 + f] = o * dv;
}

// ---------------- fused: x3 = relu(dv*(agg+self)+b); out = relu(x3@lin1+b1)@lin2+b2 ----------------
__global__ __launch_bounds__(256) void k_agg_head(const float* __restrict__ H,
                                                  const int* __restrict__ rowptr,
                                                  const int* __restrict__ csr,
                                                  const float* __restrict__ dinv,
                                                  const float* __restrict__ bias,
                                                  const float* __restrict__ L1W,
                                                  const float* __restrict__ L1B,
                                                  const float* __restrict__ L2W,
                                                  const float* __restrict__ L2B,
                                                  float* __restrict__ out, int n) {
    __shared__ float w1[512];   // [32][16]
    __shared__ float w2[160];   // [16][10]
    __shared__ float bb1[16];
    __shared__ float bb2[10];
    int tid = threadIdx.x;
    for (int t = tid; t < 512; t += 256) w1[t] = L1W[t];
    if (tid < 160) w2[tid] = L2W[tid];
    if (tid < 16) bb1[tid] = L1B[tid];
    if (tid < 10) bb2[tid] = L2B[tid];
    __syncthreads();
    int node = blockIdx.x * 8 + (tid >> 5);
    int f = tid & 31;
    if (node >= n) return;
    int e0 = rowptr[node], e1 = rowptr[node + 1];
    const float* Hf = H + f;
    float asum = gather_sum(Hf, csr, e0, e1, f);
    float dv = dinv[node];
    float v = dv * (asum + Hf[(long)node * 32]) + bias[f];
    v = fmaxf(v, 0.f);
    int c1 = f & 15;
    float t1 = 0.f;
#pragma unroll
    for (int k = 0; k < 32; k++) {
        float vk = __shfl(v, k, 32);
        t1 += vk * w1[k * 16 + c1];
    }
    t1 = fmaxf(t1 + bb1[c1], 0.f);
    int c2 = (f < 10) ? f : 0;
    float o = 0.f;
#pragma unroll
    for (int k = 0; k < 16; k++) {
        float tk = __shfl(t1, k, 32);
        o += tk * w2[k * 10 + c2];
    }
    o += bb2[c2];
    if (f < 10) out[(long)node * 10 + f] = o;
}

extern "C" void kernel_launch(void* const* d_in, const int* in_sizes, int n_in,
                              void* d_out, int out_size, void* d_ws, size_t ws_size,
                              hipStream_t stream) {
    const float* x0 = (const float*)d_in[0];
    const int* ei = (const int*)d_in[1];
    const float* W1 = (const float*)d_in[3];
    const float* b1 = (const float*)d_in[4];
    const float* W2 = (const float*)d_in[5];
    const float* b2 = (const float*)d_in[6];
    const float* W3 = (const float*)d_in[7];
    const float* b3 = (const float*)d_in[8];
    const float* l1W = (const float*)d_in[9];
    const float* l1b = (const float*)d_in[10];
    const float* l2W = (const float*)d_in[11];
    const float* l2b = (const float*)d_in[12];

    const int E = in_sizes[1] / 2;
    const int N = N_NODES;

    char* w = (char*)d_ws;
    // bp (25.6 MB) aliases h+xb: dead before k_gemm1 writes h.
    // Bh/Bl (64 KB) alias gh: gh is dead after k_bucketize consumes the offsets.
    float* h      = (float*)(w);                   // 12,800,000 B
    float* xb     = (float*)(w + 12800000);        // 12,800,000 B
    int2*  bp     = (int2*) (w);                   // 25,600,000 B (alias)
    int*   gh     = (int*)  (w + 25600000);        //    400,384 B  (HBLK*NBUK)
    unsigned* Bh  = (unsigned*)(w + 25600000);     //     32,768 B  (alias of gh)
    unsigned* Bl  = (unsigned*)(w + 25632768);     //     32,768 B  (alias of gh)
    int*   btot   = (int*)  (w + 26000384);        //      1,564 B
    int*   bbase  = (int*)  (w + 26001948);        //      1,568 B  (NBUK+1)
    int*   rowptr = (int*)  (w + 26003516);        //    400,016 B
    float* dinv   = (float*)(w + 26403532);        //    400,000 B
    int*   csr    = (int*)  (w + 26803532);        // 12,800,000 B
    int*   mode   = (int*)  (w + 39603532);        //          4 B

    const int chunk = (E + HBLK - 1) / HBLK;   // 12500
    const int AGB = (N + 7) / 8;               // 12500
    const int G1B = (N + 63) / 64;             // 1563 (4 waves x 16 rows each)

    // --- CSR build: zero global atomics ---
    k_detect<<<1, 256, 0, stream>>>(ei, mode);
    k_hist<<<HBLK, 256, 0, stream>>>(ei, mode, gh, E, chunk);
    k_btot<<<NBUK, 256, 0, stream>>>(gh, btot);
    k_scan_btot<<<1, 512, 0, stream>>>(btot, bbase, rowptr, E);
    k_scan_cols<<<NBUK, 256, 0, stream>>>(gh, bbase);
    k_bucketize<<<HBLK, 256, 0, stream>>>(ei, mode, gh, bp, E, chunk);
    k_prepw<<<32, 256, 0, stream>>>(W1, Bh, Bl);   // gh dead from here on
    k_build_csr<<<NBUK, 256, 0, stream>>>(bp, bbase, rowptr, dinv, csr);

    // --- layers (transform + head fused into aggregation epilogues; H pre-scaled by dinv) ---
    k_gemm1<<<G1B, 256, 0, stream>>>(x0, Bh, Bl, dinv, h);
    k_agg_mm<<<AGB, 256, 0, stream>>>(h, rowptr, csr, dinv, b1, W2, xb, N);
    k_agg_mm<<<AGB, 256, 0, stream>>>(xb, rowptr, csr, dinv, b2, W3, h, N);
    k_agg_head<<<AGB, 256, 0, stream>>>(h, rowptr, csr, dinv, b3,
                                        l1W, l1b, l2W, l2b, (float*)d_out, N);
}